// Round 15
// baseline (128.752 us; speedup 1.0000x reference)
//
#include <hip/hip_runtime.h>

typedef __bf16 bf16;
typedef bf16 bf16x4 __attribute__((ext_vector_type(4)));
typedef bf16 bf16x8 __attribute__((ext_vector_type(8)));
typedef float f32x4 __attribute__((ext_vector_type(4)));
typedef int ivec4 __attribute__((ext_vector_type(4)));

#define PTOT 147456   // 384*384
#define N384 384

static __device__ __forceinline__ f32x4 mfma16(bf16x8 a, bf16x8 b, f32x4 c) {
  return __builtin_amdgcn_mfma_f32_16x16x32_bf16(a, b, c, 0, 0, 0);
}

// async global->LDS, 16B per lane: LDS dest = base + lane*16 (wave-uniform base)
static __device__ __forceinline__ void gload_lds16(const bf16* g, bf16* lds) {
  __builtin_amdgcn_global_load_lds(
      (const __attribute__((address_space(1))) void*)g,
      (__attribute__((address_space(3))) void*)lds, 16, 0, 0);
}

// ---------------------------------------------------------------------------
// k_prep (40 blocks = 5 mats x 8 ch-tiles): repack weights to bf16 frag order.
// m<4: phase-interleaved for k1: wt[ ((n*16 + m*4 + ks)*64 + l)*8 + e ]
//      = W[k=ks*32+(l>>4)*8+e][ch=n*16+(l&15)]
// m==4 (W_z): wtz[ ((n*4+ks)*64 + l)*8 + e ] at wt+4*16384 (for k3).
// ---------------------------------------------------------------------------
__global__ __launch_bounds__(256) void k_prep(
    const float* __restrict__ w0, const float* __restrict__ w1,
    const float* __restrict__ w2, const float* __restrict__ w3,
    const float* __restrict__ w4, bf16* __restrict__ wt)
{
  const int m = blockIdx.x >> 3, n = blockIdx.x & 7;
  const float* src = (m == 0) ? w0 : (m == 1) ? w1 : (m == 2) ? w2 : (m == 3) ? w3 : w4;
  const int t = threadIdx.x;
  const int ks = t >> 6, l = t & 63;
  const int ch = n * 16 + (l & 15);
  const int kb = ks * 32 + (l >> 4) * 8;
  bf16 tmp[8] __attribute__((aligned(16)));
  #pragma unroll
  for (int e = 0; e < 8; ++e)
    tmp[e] = (bf16)src[(size_t)(kb + e) * 128 + ch];
  bf16* dst = (m < 4)
      ? wt + (size_t)((n * 16 + m * 4 + ks) * 64 + l) * 8
      : wt + 4 * 16384 + (size_t)((n * 4 + ks) * 64 + l) * 8;
  *(ivec4*)dst = *(const ivec4*)tmp;
}

// ---------------------------------------------------------------------------
// k1 v10: barrier-free per-wave weight pipeline.
// 256 threads (4 waves), 64 positions. Wave w: pair=w&1, pos-half=w>>1.
// Each wave stages ITS OWN 8 chunks/phase (contiguous in prep layout:
// chunks p*16 + pair*8 + 0..7) into a wave-private LDS double buffer and
// syncs with per-wave counted vmcnt -- NO block barriers in the loop
// (the diagnosed ~1700 idle cy/phase was barrier convergence + full drain).
// Outstanding-op ledger (in-order vmem completion):
//   pre-loop vmcnt(0) clears everything (incl. compiler loads);
//   at phase p>=1: [p gloads(8)][p-1 stores(2)][p+1 gloads(8)] -> vmcnt(10);
//   at p==7: [p7 gloads(8)][p6 stores(2)] -> vmcnt(2); p==0 already drained.
// LDS: xn 16 KB + 4 waves x 16 KB dbuf = 80 KB -> 2 blocks/CU.
// Stores stay immediate per phase (R9/R12: moving them amplifies WRITE_SIZE).
// ---------------------------------------------------------------------------
__global__ __launch_bounds__(256, 2) void k1_ln_proj(
    const float* __restrict__ x, const float* __restrict__ mask,
    const float* __restrict__ gamma, const float* __restrict__ beta,
    const float* __restrict__ bap, const float* __restrict__ bbp,
    const bf16* __restrict__ wt,
    bf16* __restrict__ a_t, bf16* __restrict__ b_t)
{
  __shared__ __align__(16) bf16 xnb[8192];    // 16 KB xn (not reused)
  __shared__ __align__(16) bf16 wl[32768];    // 64 KB: wave w at wl+w*8192

  const int t = threadIdx.x;
  const int l = t & 63;
  const int w = t >> 6;
  const int p0 = blockIdx.x << 6;
  const int fr = l & 15, fq = l >> 4;
  const int pair = w & 1;
  const int prow0 = (w >> 1) * 32;

  const bf16* wsrc = wt + l * 8;
  bf16* wavebuf = wl + w * 8192;             // [2][4096] per wave

  // ---- issue phase-0 staging (8 chunks, wave-private; overlaps LN) ----
  #pragma unroll
  for (int j = 0; j < 8; ++j)
    gload_lds16(wsrc + ((pair * 8 + j) << 9), wavebuf + j * 512);

  // ---- mask -> registers (broadcast 16B loads, L2) ----
  f32x4 m4r[2];
  m4r[0] = *(const f32x4*)(mask + p0 + prow0 + fq * 4);
  m4r[1] = *(const f32x4*)(mask + p0 + prow0 + 16 + fq * 4);

  // ---- LayerNorm: 2 rounds x 32 rows; thread -> row (t>>3), 16 channels ----
  const int csub = (t & 7) << 4;
  f32x4 g4[4], bt4[4];
  #pragma unroll
  for (int i = 0; i < 4; ++i) {
    g4[i]  = *(const f32x4*)(gamma + csub + i * 4);
    bt4[i] = *(const f32x4*)(beta  + csub + i * 4);
  }
  #pragma unroll
  for (int it = 0; it < 2; ++it) {
    const int row = (t >> 3) + it * 32;
    f32x4 v[4];
    const float* xb = x + (size_t)(p0 + row) * 128 + csub;
    #pragma unroll
    for (int i = 0; i < 4; ++i) v[i] = *(const f32x4*)(xb + i * 4);

    float s = 0.f, s2 = 0.f;
    #pragma unroll
    for (int i = 0; i < 4; ++i)
      #pragma unroll
      for (int j = 0; j < 4; ++j) { const float f = v[i][j]; s += f; s2 += f * f; }
    #pragma unroll
    for (int m = 1; m < 8; m <<= 1) {
      s  += __shfl_xor(s, m, 64);
      s2 += __shfl_xor(s2, m, 64);
    }
    const float mu = s * (1.f / 128.f);
    const float rs = rsqrtf(s2 * (1.f / 128.f) - mu * mu + 1e-5f);

    bf16x8 xv0, xv1;
    #pragma unroll
    for (int i = 0; i < 4; ++i)
      #pragma unroll
      for (int j = 0; j < 4; ++j) {
        const float f = (v[i][j] - mu) * rs * g4[i][j] + bt4[i][j];
        const int e = i * 4 + j;
        if (e < 8) xv0[e] = (bf16)f; else xv1[e - 8] = (bf16)f;
      }
    const int sw = (row & 7) << 3;
    *(bf16x8*)&xnb[row * 128 + (csub ^ sw)]       = xv0;
    *(bf16x8*)&xnb[row * 128 + ((csub + 8) ^ sw)] = xv1;
  }
  __syncthreads();   // xn visible to all waves (only barrier in the kernel)

  // ---- A fragments (held in registers for the whole kernel) ----
  bf16x8 af[2][4];
  #pragma unroll
  for (int mi = 0; mi < 2; ++mi)
    #pragma unroll
    for (int ks = 0; ks < 4; ++ks) {
      const int row = prow0 + mi * 16 + fr;
      af[mi][ks] = *(const bf16x8*)&xnb[row * 128 + ((ks * 32 + fq * 8) ^ ((fr & 7) << 3))];
    }

  const float* bp = pair ? bbp : bap;
  bf16* dst = pair ? b_t : a_t;
  float biasv[8];
  #pragma unroll
  for (int p = 0; p < 8; ++p) biasv[p] = bp[p * 16 + fr];

  // drain ALL outstanding vmem (phase-0 gloads + any compiler loads) so the
  // in-loop hand-counted vmcnt ledger sees only this wave's loop ops.
  asm volatile("s_waitcnt vmcnt(0)" ::: "memory");
  __builtin_amdgcn_sched_barrier(0);

  #pragma unroll
  for (int p = 0; p < 8; ++p) {
    if (p < 7) {   // stage phase p+1 into this wave's idle half
      bf16* nb = wavebuf + ((p + 1) & 1) * 4096;
      #pragma unroll
      for (int j = 0; j < 8; ++j)
        gload_lds16(wsrc + (((p + 1) * 16 + pair * 8 + j) << 9), nb + j * 512);
      __builtin_amdgcn_sched_barrier(0);
    }
    // per-wave counted wait: drain phase-p gloads, keep newer ops in flight
    if (p >= 1 && p < 7) {
      asm volatile("s_waitcnt vmcnt(10)" ::: "memory");
      __builtin_amdgcn_sched_barrier(0);
    } else if (p == 7) {
      asm volatile("s_waitcnt vmcnt(2)" ::: "memory");
      __builtin_amdgcn_sched_barrier(0);
    }
    const bf16* buf = wavebuf + (p & 1) * 4096 + l * 8;

    f32x4 aG0 = (f32x4){0.f, 0.f, 0.f, 0.f};
    f32x4 aG1 = (f32x4){0.f, 0.f, 0.f, 0.f};
    #pragma unroll
    for (int ks = 0; ks < 4; ++ks) {
      const bf16x8 bv = *(const bf16x8*)(buf + 2048 + ks * 512);   // gate
      aG0 = mfma16(af[0][ks], bv, aG0);
      aG1 = mfma16(af[1][ks], bv, aG1);
    }
    f32x4 aP0 = (f32x4){0.f, 0.f, 0.f, 0.f};
    f32x4 aP1 = (f32x4){0.f, 0.f, 0.f, 0.f};
    #pragma unroll
    for (int ks = 0; ks < 4; ++ks) {
      const bf16x8 bv = *(const bf16x8*)(buf + ks * 512);          // proj
      aP0 = mfma16(af[0][ks], bv, aP0);
      aP1 = mfma16(af[1][ks], bv, aP1);
    }
    const int ch = p * 16 + fr;
    const float bias = biasv[p];
    #pragma unroll
    for (int mi = 0; mi < 2; ++mi) {
      const f32x4 aG = mi ? aG1 : aG0;
      const f32x4 aP = mi ? aP1 : aP0;
      const int pb = prow0 + mi * 16 + fq * 4;
      const f32x4 m4 = m4r[mi];
      bf16x4 pk;
      #pragma unroll
      for (int r = 0; r < 4; ++r) {
        const float sg = 1.f / (1.f + __expf(-aG[r]));
        pk[r] = (bf16)((aP[r] + bias) * sg * m4[r]);
      }
      *(bf16x4*)(dst + (size_t)ch * PTOT + p0 + pb) = pk;
    }
  }
}

// ---------------------------------------------------------------------------
// k2 v4 (frozen): per-channel GEMM O_c = A_c * B_c (384x384), 192x192 tile,
// BK=32, double-buffered, ONE barrier per kt. 36 MFMA/wave/kt.
// Grid 512 = 8 XCD x 16 ch x 4 tiles -> exactly 2 blocks/CU.
// ---------------------------------------------------------------------------
__global__ __launch_bounds__(256, 2) void k2_tri(
    const bf16* __restrict__ a_t, const bf16* __restrict__ b_t, bf16* __restrict__ o_t)
{
  __shared__ __align__(16) bf16 As[2][6144];   // [row 192][k 32] swizzled
  __shared__ __align__(16) bf16 Bs[2][6144];   // [j 192][k 32] swizzled
  const int t = threadIdx.x, l = t & 63, w = t >> 6;
  const int fr = l & 15, fq = l >> 4;
  const int bid = blockIdx.x;
  const int xcd = bid & 7, idx = bid >> 3;
  const int c  = xcd * 16 + (idx >> 2);        // channel
  const int ti = idx & 3;                      // tile 0..3
  const int i0 = (ti >> 1) * 192, j0 = (ti & 1) * 192;
  const bf16* ap = a_t + (size_t)c * PTOT;
  const bf16* bp = b_t + (size_t)c * PTOT;
  const int wm = (w >> 1) * 96, wn = (w & 1) * 96;
  const int arA = w * 48 + (l >> 2);
  const int kp1 = t >> 4, jb1 = (t & 15) * 8;          // all threads
  const int kp2 = t >> 3, jb2 = 128 + (t & 7) * 8;     // t < 128 only
  const bool two = t < 128;

  f32x4 acc[6][6];
  #pragma unroll
  for (int mi = 0; mi < 6; ++mi)
    #pragma unroll
    for (int ni = 0; ni < 6; ++ni) acc[mi][ni] = (f32x4){0.f, 0.f, 0.f, 0.f};

  ivec4 g10, g11, g20, g21;
  #pragma unroll
  for (int jcall = 0; jcall < 3; ++jcall) {
    const int row = arA + jcall * 16;
    const int scol = ((l & 3) ^ ((row >> 3) & 3)) << 3;
    gload_lds16(ap + (size_t)(i0 + row) * N384 + scol, &As[0][w * 1536 + jcall * 512]);
  }
  g10 = *(const ivec4*)(bp + (size_t)(2 * kp1) * N384 + j0 + jb1);
  g11 = *(const ivec4*)(bp + (size_t)(2 * kp1 + 1) * N384 + j0 + jb1);
  if (two) {
    g20 = *(const ivec4*)(bp + (size_t)(2 * kp2) * N384 + j0 + jb2);
    g21 = *(const ivec4*)(bp + (size_t)(2 * kp2 + 1) * N384 + j0 + jb2);
  }
  {
    union { ivec4 v; unsigned short u[8]; } ua, ub;
    ua.v = g10; ub.v = g11;
    #pragma unroll
    for (int e = 0; e < 8; ++e) {
      const int j = jb1 + e;
      const unsigned int pk = (unsigned int)ua.u[e] | ((unsigned int)ub.u[e] << 16);
      *(unsigned int*)&Bs[0][j * 32 + (((kp1 >> 2) ^ ((j >> 3) & 3)) << 3) + ((kp1 & 3) << 1)] = pk;
    }
    if (two) {
      ua.v = g20; ub.v = g21;
      #pragma unroll
      for (int e = 0; e < 8; ++e) {
        const int j = jb2 + e;
        const unsigned int pk = (unsigned int)ua.u[e] | ((unsigned int)ub.u[e] << 16);
        *(unsigned int*)&Bs[0][j * 32 + (((kp2 >> 2) ^ ((j >> 3) & 3)) << 3) + ((kp2 & 3) << 1)] = pk;
      }
    }
  }

  for (int kt = 0; kt < 12; ++kt) {
    __syncthreads();
    const int cur = kt & 1;
    bf16x8 af[6], bfv[6];
    #pragma unroll
    for (int mi = 0; mi < 6; ++mi) {
      const int row = wm + mi * 16 + fr;
      af[mi] = *(const bf16x8*)&As[cur][row * 32 + ((fq ^ ((row >> 3) & 3)) << 3)];
    }
    #pragma unroll
    for (int ni = 0; ni < 6; ++ni) {
      const int j = wn + ni * 16 + fr;
      bfv[ni] = *(const bf16x8*)&Bs[cur][j * 32 + ((fq ^ ((j >> 3) & 3)) << 3)];
    }
    if (kt < 11) {
      const int k0 = (kt + 1) * 32;
      const int nxt = cur ^ 1;
      #pragma unroll
      for (int jcall = 0; jcall < 3; ++jcall) {
        const int row = arA + jcall * 16;
        const int scol = ((l & 3) ^ ((row >> 3) & 3)) << 3;
        gload_lds16(ap + (size_t)(i0 + row) * N384 + k0 + scol,
                    &As[nxt][w * 1536 + jcall * 512]);
      }
      g10 = *(const ivec4*)(bp + (size_t)(k0 + 2 * kp1) * N384 + j0 + jb1);
      g11 = *(const ivec4*)(bp + (size_t)(k0 + 2 * kp1 + 1) * N384 + j0 + jb1);
      if (two) {
        g20 = *(const ivec4*)(bp + (size_t)(k0 + 2 * kp2) * N384 + j0 + jb2);
        g21 = *(const ivec4*)(bp + (size_t)(k0 + 2 * kp2 + 1) * N384 + j0 + jb2);
      }
    }
    #pragma unroll
    for (int mi = 0; mi < 6; ++mi)
      #pragma unroll
      for (int ni = 0; ni < 6; ++ni)
        acc[mi][ni] = mfma16(bfv[ni], af[mi], acc[mi][ni]);
    if (kt < 11) {
      const int nxt = cur ^ 1;
      union { ivec4 v; unsigned short u[8]; } ua, ub;
      ua.v = g10; ub.v = g11;
      #pragma unroll
      for (int e = 0; e < 8; ++e) {
        const int j = jb1 + e;
        const unsigned int pk = (unsigned int)ua.u[e] | ((unsigned int)ub.u[e] << 16);
        *(unsigned int*)&Bs[nxt][j * 32 + (((kp1 >> 2) ^ ((j >> 3) & 3)) << 3) + ((kp1 & 3) << 1)] = pk;
      }
      if (two) {
        ua.v = g20; ub.v = g21;
        #pragma unroll
        for (int e = 0; e < 8; ++e) {
          const int j = jb2 + e;
          const unsigned int pk = (unsigned int)ua.u[e] | ((unsigned int)ub.u[e] << 16);
          *(unsigned int*)&Bs[nxt][j * 32 + (((kp2 >> 2) ^ ((j >> 3) & 3)) << 3) + ((kp2 & 3) << 1)] = pk;
        }
      }
    }
  }

  bf16* op = o_t + (size_t)c * PTOT;
  #pragma unroll
  for (int mi = 0; mi < 6; ++mi) {
    const int irow = i0 + wm + mi * 16 + fr;
    #pragma unroll
    for (int ni = 0; ni < 6; ++ni) {
      const int jcol = j0 + wn + ni * 16 + fq * 4;
      bf16x4 pk;
      #pragma unroll
      for (int r = 0; r < 4; ++r) pk[r] = (bf16)acc[mi][ni][r];
      *(bf16x4*)(op + (size_t)irow * N384 + jcol) = pk;
    }
  }
}

// ---------------------------------------------------------------------------
// k3 v2 (frozen): out = x + (o @ W_z + b_z). 64 positions/block.
// ---------------------------------------------------------------------------
__global__ __launch_bounds__(256) void k3_out(
    const bf16* __restrict__ o_t, const bf16* __restrict__ wtz,
    const float* __restrict__ x, const float* __restrict__ bz,
    float* __restrict__ out)
{
  __shared__ __align__(16) bf16 Ao[64 * 128];
  const int t = threadIdx.x, l = t & 63, w = t >> 6;
  const int fr = l & 15, fq = l >> 4;
  const int p0 = blockIdx.x << 6;
  const int ps = t & 7, cb = t >> 3;   // p-seg, ch-pair base

  #pragma unroll
  for (int rep = 0; rep < 2; ++rep) {
    const int cc = cb + 32 * rep;      // ch-pair index 0..63
    ivec4 d0 = *(const ivec4*)(o_t + (size_t)(2 * cc) * PTOT + p0 + ps * 8);
    ivec4 d1 = *(const ivec4*)(o_t + (size_t)(2 * cc + 1) * PTOT + p0 + ps * 8);
    union { ivec4 v; unsigned short u[8]; } ua, ub;
    ua.v = d0; ub.v = d1;
    #pragma unroll
    for (int e = 0; e < 8; ++e) {
      const int p = ps * 8 + e;
      const unsigned int pk = (unsigned int)ua.u[e] | ((unsigned int)ub.u[e] << 16);
      *(unsigned int*)&Ao[p * 128 + (((cc >> 2) ^ (p & 15)) << 3) + ((cc & 3) << 1)] = pk;
    }
  }
  __syncthreads();

  bf16x8 af[4];
  #pragma unroll
  for (int ks = 0; ks < 4; ++ks) {
    const int p = w * 16 + fr;         // p & 15 == fr
    af[ks] = *(const bf16x8*)&Ao[p * 128 + (((ks * 4 + fq) ^ fr) << 3)];
  }

  const bf16* wzf = wtz + l * 8;
  f32x4 acc[8];
  #pragma unroll
  for (int n = 0; n < 8; ++n) acc[n] = (f32x4){0.f, 0.f, 0.f, 0.f};
  #pragma unroll
  for (int n = 0; n < 8; ++n)
    #pragma unroll
    for (int ks = 0; ks < 4; ++ks) {
      const bf16x8 bfv = *(const bf16x8*)(wzf + ((n * 4 + ks) << 9));
      acc[n] = mfma16(bfv, af[ks], acc[n]);
    }

  const int pp = p0 + w * 16 + fr;
  #pragma unroll
  for (int n = 0; n < 8; ++n) {
    const int ch = n * 16 + fq * 4;
    const f32x4 b4 = *(const f32x4*)(bz + ch);
    const size_t idx = (size_t)pp * 128 + ch;
    const f32x4 x4 = *(const f32x4*)(x + idx);
    f32x4 o4;
    #pragma unroll
    for (int r = 0; r < 4; ++r) o4[r] = x4[r] + acc[n][r] + b4[r];
    *(f32x4*)(out + idx) = o4;
  }
}

// ---------------------------------------------------------------------------
extern "C" void kernel_launch(void* const* d_in, const int* in_sizes, int n_in,
                              void* d_out, int out_size, void* d_ws, size_t ws_size,
                              hipStream_t stream) {
  const float* x     = (const float*)d_in[0];
  const float* mask  = (const float*)d_in[1];
  const float* gamma = (const float*)d_in[2];
  const float* beta  = (const float*)d_in[3];
  const float* Wap   = (const float*)d_in[4];
  const float* bap   = (const float*)d_in[5];
  const float* Wag   = (const float*)d_in[6];
  const float* Wbp   = (const float*)d_in[7];
  const float* bbp   = (const float*)d_in[8];
  const float* Wbg   = (const float*)d_in[9];
  const float* Wz    = (const float*)d_in[10];
  const float* bz    = (const float*)d_in[11];

  char* ws = (char*)d_ws;
  bf16* wt  = (bf16*)ws;                         // 5*128*128 bf16 = 160KB
  bf16* a_t = (bf16*)(ws + 163840);              // [128][147456] bf16
  bf16* b_t = a_t + (size_t)128 * PTOT;
  bf16* o_t = b_t + (size_t)128 * PTOT;
  float* out = (float*)d_out;

  k_prep<<<40, 256, 0, stream>>>(Wap, Wag, Wbp, Wbg, Wz, wt);
  k1_ln_proj<<<2304, 256, 0, stream>>>(x, mask, gamma, beta, bap, bbp, wt, a_t, b_t);
  k2_tri<<<512, 256, 0, stream>>>(a_t, b_t, o_t);
  k3_out<<<2304, 256, 0, stream>>>(o_t, wt + 4 * 16384, x, bz, out);
}

// Round 16
// 126.446 us; speedup vs baseline: 1.0182x; 1.0182x over previous
//
#include <hip/hip_runtime.h>

typedef __bf16 bf16;
typedef bf16 bf16x4 __attribute__((ext_vector_type(4)));
typedef bf16 bf16x8 __attribute__((ext_vector_type(8)));
typedef float f32x4 __attribute__((ext_vector_type(4)));
typedef int ivec4 __attribute__((ext_vector_type(4)));

#define PTOT 147456   // 384*384
#define N384 384

static __device__ __forceinline__ f32x4 mfma16(bf16x8 a, bf16x8 b, f32x4 c) {
  return __builtin_amdgcn_mfma_f32_16x16x32_bf16(a, b, c, 0, 0, 0);
}

// async global->LDS, 16B per lane: LDS dest = base + lane*16 (wave-uniform base)
static __device__ __forceinline__ void gload_lds16(const bf16* g, bf16* lds) {
  __builtin_amdgcn_global_load_lds(
      (const __attribute__((address_space(1))) void*)g,
      (__attribute__((address_space(3))) void*)lds, 16, 0, 0);
}

// ---------------------------------------------------------------------------
// k_prep (40 blocks = 5 mats x 8 ch-tiles): repack weights to bf16 frag order.
// m<4: phase-interleaved for k1: wt[ ((n*16 + m*4 + ks)*64 + l)*8 + e ]
//      = W[k=ks*32+(l>>4)*8+e][ch=n*16+(l&15)]
// m==4 (W_z): wtz[ ((n*4+ks)*64 + l)*8 + e ] at wt+4*16384 (for k3).
// ---------------------------------------------------------------------------
__global__ __launch_bounds__(256) void k_prep(
    const float* __restrict__ w0, const float* __restrict__ w1,
    const float* __restrict__ w2, const float* __restrict__ w3,
    const float* __restrict__ w4, bf16* __restrict__ wt)
{
  const int m = blockIdx.x >> 3, n = blockIdx.x & 7;
  const float* src = (m == 0) ? w0 : (m == 1) ? w1 : (m == 2) ? w2 : (m == 3) ? w3 : w4;
  const int t = threadIdx.x;
  const int ks = t >> 6, l = t & 63;
  const int ch = n * 16 + (l & 15);
  const int kb = ks * 32 + (l >> 4) * 8;
  bf16 tmp[8] __attribute__((aligned(16)));
  #pragma unroll
  for (int e = 0; e < 8; ++e)
    tmp[e] = (bf16)src[(size_t)(kb + e) * 128 + ch];
  bf16* dst = (m < 4)
      ? wt + (size_t)((n * 16 + m * 4 + ks) * 64 + l) * 8
      : wt + 4 * 16384 + (size_t)((n * 4 + ks) * 64 + l) * 8;
  *(ivec4*)dst = *(const ivec4*)tmp;
}

// ---------------------------------------------------------------------------
// k1 v11: v6 envelope + doubled per-phase work. 256 threads (4 waves),
// 128 positions/block (grid 1152). Wave w owns pos w*32..+31 and pair-loops
// over BOTH a and b: 32 MFMA + 4 stores per phase (2x v6) -> fixed per-phase
// cost (barrier convergence + drain) amortized over 2x output; weight L2
// traffic halves. Both 16KB weight dbuf halves overlay xn's 32KB after
// fragment extraction. Stores immediate (R9/R12: moving them amplifies
// WRITE_SIZE). Uniform counted vmcnt(4) per barrier: ledger at wait point =
// [st p-1 (4)][gl p+1 (4)][st p (4)] -> drains st p-1 + gl p+1, leaves st p.
// LDS 32 KB -> 5 blocks/CU.
// ---------------------------------------------------------------------------
__global__ __launch_bounds__(256, 5) void k1_ln_proj(
    const float* __restrict__ x, const float* __restrict__ mask,
    const float* __restrict__ gamma, const float* __restrict__ beta,
    const float* __restrict__ bap, const float* __restrict__ bbp,
    const bf16* __restrict__ wt,
    bf16* __restrict__ a_t, bf16* __restrict__ b_t)
{
  __shared__ __align__(16) bf16 xnb[16384];  // 32 KB: xn[128][128] -> 2 wbufs

  const int t = threadIdx.x;
  const int l = t & 63;
  const int w = t >> 6;
  const int p0 = blockIdx.x << 7;
  const int fr = l & 15, fq = l >> 4;
  const int prow0 = w * 32;

  // ---- mask -> registers (broadcast 16B loads, L2) ----
  f32x4 m4r[2];
  m4r[0] = *(const f32x4*)(mask + p0 + prow0 + fq * 4);
  m4r[1] = *(const f32x4*)(mask + p0 + prow0 + 16 + fq * 4);

  // ---- LayerNorm: 4 rounds x 32 rows; thread -> row (t>>3), 16 channels ----
  const int csub = (t & 7) << 4;
  f32x4 g4[4], bt4[4];
  #pragma unroll
  for (int i = 0; i < 4; ++i) {
    g4[i]  = *(const f32x4*)(gamma + csub + i * 4);
    bt4[i] = *(const f32x4*)(beta  + csub + i * 4);
  }
  #pragma unroll
  for (int it = 0; it < 4; ++it) {
    const int row = (t >> 3) + it * 32;
    f32x4 v[4];
    const float* xb = x + (size_t)(p0 + row) * 128 + csub;
    #pragma unroll
    for (int i = 0; i < 4; ++i) v[i] = *(const f32x4*)(xb + i * 4);

    float s = 0.f, s2 = 0.f;
    #pragma unroll
    for (int i = 0; i < 4; ++i)
      #pragma unroll
      for (int j = 0; j < 4; ++j) { const float f = v[i][j]; s += f; s2 += f * f; }
    #pragma unroll
    for (int m = 1; m < 8; m <<= 1) {
      s  += __shfl_xor(s, m, 64);
      s2 += __shfl_xor(s2, m, 64);
    }
    const float mu = s * (1.f / 128.f);
    const float rs = rsqrtf(s2 * (1.f / 128.f) - mu * mu + 1e-5f);

    bf16x8 xv0, xv1;
    #pragma unroll
    for (int i = 0; i < 4; ++i)
      #pragma unroll
      for (int j = 0; j < 4; ++j) {
        const float f = (v[i][j] - mu) * rs * g4[i][j] + bt4[i][j];
        const int e = i * 4 + j;
        if (e < 8) xv0[e] = (bf16)f; else xv1[e - 8] = (bf16)f;
      }
    const int sw = (row & 7) << 3;
    *(bf16x8*)&xnb[row * 128 + (csub ^ sw)]       = xv0;
    *(bf16x8*)&xnb[row * 128 + ((csub + 8) ^ sw)] = xv1;
  }
  __syncthreads();   // xn complete

  // ---- A fragments (held in registers for the whole kernel) ----
  bf16x8 af[2][4];
  #pragma unroll
  for (int mi = 0; mi < 2; ++mi)
    #pragma unroll
    for (int ks = 0; ks < 4; ++ks) {
      const int row = prow0 + mi * 16 + fr;
      af[mi][ks] = *(const bf16x8*)&xnb[row * 128 + ((ks * 32 + fq * 8) ^ ((fr & 7) << 3))];
    }
  __syncthreads();   // all waves done reading xn; reuse as weight buffers

  float biasA[8], biasB[8];
  #pragma unroll
  for (int p = 0; p < 8; ++p) { biasA[p] = bap[p * 16 + fr]; biasB[p] = bbp[p * 16 + fr]; }

  const bf16* wsrc = wt + l * 8;
  const int c0 = w * 4;

  // ---- prologue: stage phase 0 into buf0 (xnb lower half) ----
  #pragma unroll
  for (int j = 0; j < 4; ++j)
    gload_lds16(wsrc + ((c0 + j) << 9), xnb + (c0 + j) * 512);
  asm volatile("s_waitcnt vmcnt(0)" ::: "memory");   // clears ALL (incl. bias loads)
  __builtin_amdgcn_sched_barrier(0);
  __syncthreads();   // phase-0 staging visible to all waves

  #pragma unroll
  for (int p = 0; p < 8; ++p) {
    if (p < 7) {   // stage phase p+1 into the idle half
      bf16* nb = xnb + ((p + 1) & 1) * 8192;
      #pragma unroll
      for (int j = 0; j < 4; ++j)
        gload_lds16(wsrc + (((p + 1) * 16 + c0 + j) << 9), nb + (c0 + j) * 512);
      __builtin_amdgcn_sched_barrier(0);   // pin gload issue at phase top
    }
    const bf16* buf = xnb + (p & 1) * 8192 + l * 8;
    #pragma unroll
    for (int pair = 0; pair < 2; ++pair) {
      const bf16* wpl = buf + pair * 4096;          // proj chunks (4 ks)
      const bf16* wgl = wpl + 2048;                 // gate chunks
      f32x4 aG0 = (f32x4){0.f, 0.f, 0.f, 0.f};
      f32x4 aG1 = (f32x4){0.f, 0.f, 0.f, 0.f};
      #pragma unroll
      for (int ks = 0; ks < 4; ++ks) {
        const bf16x8 bv = *(const bf16x8*)(wgl + ks * 512);
        aG0 = mfma16(af[0][ks], bv, aG0);
        aG1 = mfma16(af[1][ks], bv, aG1);
      }
      f32x4 aP0 = (f32x4){0.f, 0.f, 0.f, 0.f};
      f32x4 aP1 = (f32x4){0.f, 0.f, 0.f, 0.f};
      #pragma unroll
      for (int ks = 0; ks < 4; ++ks) {
        const bf16x8 bv = *(const bf16x8*)(wpl + ks * 512);
        aP0 = mfma16(af[0][ks], bv, aP0);
        aP1 = mfma16(af[1][ks], bv, aP1);
      }
      const int ch = p * 16 + fr;
      const float bias = pair ? biasB[p] : biasA[p];
      bf16* dst = pair ? b_t : a_t;
      #pragma unroll
      for (int mi = 0; mi < 2; ++mi) {
        const f32x4 aG = mi ? aG1 : aG0;
        const f32x4 aP = mi ? aP1 : aP0;
        const f32x4 m4 = m4r[mi];
        bf16x4 pk;
        #pragma unroll
        for (int r = 0; r < 4; ++r) {
          const float sg = 1.f / (1.f + __expf(-aG[r]));
          pk[r] = (bf16)((aP[r] + bias) * sg * m4[r]);
        }
        *(bf16x4*)(dst + (size_t)ch * PTOT + p0 + prow0 + mi * 16 + fq * 4) = pk;
      }
    }
    if (p < 7) {
      // drain st(p-1) + gl(p+1); leave this phase's 4 stores in flight
      asm volatile("s_waitcnt vmcnt(4)" ::: "memory");
      __builtin_amdgcn_sched_barrier(0);
      __builtin_amdgcn_s_barrier();
    }
  }
}

// ---------------------------------------------------------------------------
// k2 v4 (frozen): per-channel GEMM O_c = A_c * B_c (384x384), 192x192 tile,
// BK=32, double-buffered, ONE barrier per kt. 36 MFMA/wave/kt.
// Grid 512 = 8 XCD x 16 ch x 4 tiles -> exactly 2 blocks/CU.
// ---------------------------------------------------------------------------
__global__ __launch_bounds__(256, 2) void k2_tri(
    const bf16* __restrict__ a_t, const bf16* __restrict__ b_t, bf16* __restrict__ o_t)
{
  __shared__ __align__(16) bf16 As[2][6144];   // [row 192][k 32] swizzled
  __shared__ __align__(16) bf16 Bs[2][6144];   // [j 192][k 32] swizzled
  const int t = threadIdx.x, l = t & 63, w = t >> 6;
  const int fr = l & 15, fq = l >> 4;
  const int bid = blockIdx.x;
  const int xcd = bid & 7, idx = bid >> 3;
  const int c  = xcd * 16 + (idx >> 2);        // channel
  const int ti = idx & 3;                      // tile 0..3
  const int i0 = (ti >> 1) * 192, j0 = (ti & 1) * 192;
  const bf16* ap = a_t + (size_t)c * PTOT;
  const bf16* bp = b_t + (size_t)c * PTOT;
  const int wm = (w >> 1) * 96, wn = (w & 1) * 96;
  const int arA = w * 48 + (l >> 2);
  const int kp1 = t >> 4, jb1 = (t & 15) * 8;          // all threads
  const int kp2 = t >> 3, jb2 = 128 + (t & 7) * 8;     // t < 128 only
  const bool two = t < 128;

  f32x4 acc[6][6];
  #pragma unroll
  for (int mi = 0; mi < 6; ++mi)
    #pragma unroll
    for (int ni = 0; ni < 6; ++ni) acc[mi][ni] = (f32x4){0.f, 0.f, 0.f, 0.f};

  ivec4 g10, g11, g20, g21;
  #pragma unroll
  for (int jcall = 0; jcall < 3; ++jcall) {
    const int row = arA + jcall * 16;
    const int scol = ((l & 3) ^ ((row >> 3) & 3)) << 3;
    gload_lds16(ap + (size_t)(i0 + row) * N384 + scol, &As[0][w * 1536 + jcall * 512]);
  }
  g10 = *(const ivec4*)(bp + (size_t)(2 * kp1) * N384 + j0 + jb1);
  g11 = *(const ivec4*)(bp + (size_t)(2 * kp1 + 1) * N384 + j0 + jb1);
  if (two) {
    g20 = *(const ivec4*)(bp + (size_t)(2 * kp2) * N384 + j0 + jb2);
    g21 = *(const ivec4*)(bp + (size_t)(2 * kp2 + 1) * N384 + j0 + jb2);
  }
  {
    union { ivec4 v; unsigned short u[8]; } ua, ub;
    ua.v = g10; ub.v = g11;
    #pragma unroll
    for (int e = 0; e < 8; ++e) {
      const int j = jb1 + e;
      const unsigned int pk = (unsigned int)ua.u[e] | ((unsigned int)ub.u[e] << 16);
      *(unsigned int*)&Bs[0][j * 32 + (((kp1 >> 2) ^ ((j >> 3) & 3)) << 3) + ((kp1 & 3) << 1)] = pk;
    }
    if (two) {
      ua.v = g20; ub.v = g21;
      #pragma unroll
      for (int e = 0; e < 8; ++e) {
        const int j = jb2 + e;
        const unsigned int pk = (unsigned int)ua.u[e] | ((unsigned int)ub.u[e] << 16);
        *(unsigned int*)&Bs[0][j * 32 + (((kp2 >> 2) ^ ((j >> 3) & 3)) << 3) + ((kp2 & 3) << 1)] = pk;
      }
    }
  }

  for (int kt = 0; kt < 12; ++kt) {
    __syncthreads();
    const int cur = kt & 1;
    bf16x8 af[6], bfv[6];
    #pragma unroll
    for (int mi = 0; mi < 6; ++mi) {
      const int row = wm + mi * 16 + fr;
      af[mi] = *(const bf16x8*)&As[cur][row * 32 + ((fq ^ ((row >> 3) & 3)) << 3)];
    }
    #pragma unroll
    for (int ni = 0; ni < 6; ++ni) {
      const int j = wn + ni * 16 + fr;
      bfv[ni] = *(const bf16x8*)&Bs[cur][j * 32 + ((fq ^ ((j >> 3) & 3)) << 3)];
    }
    if (kt < 11) {
      const int k0 = (kt + 1) * 32;
      const int nxt = cur ^ 1;
      #pragma unroll
      for (int jcall = 0; jcall < 3; ++jcall) {
        const int row = arA + jcall * 16;
        const int scol = ((l & 3) ^ ((row >> 3) & 3)) << 3;
        gload_lds16(ap + (size_t)(i0 + row) * N384 + k0 + scol,
                    &As[nxt][w * 1536 + jcall * 512]);
      }
      g10 = *(const ivec4*)(bp + (size_t)(k0 + 2 * kp1) * N384 + j0 + jb1);
      g11 = *(const ivec4*)(bp + (size_t)(k0 + 2 * kp1 + 1) * N384 + j0 + jb1);
      if (two) {
        g20 = *(const ivec4*)(bp + (size_t)(k0 + 2 * kp2) * N384 + j0 + jb2);
        g21 = *(const ivec4*)(bp + (size_t)(k0 + 2 * kp2 + 1) * N384 + j0 + jb2);
      }
    }
    #pragma unroll
    for (int mi = 0; mi < 6; ++mi)
      #pragma unroll
      for (int ni = 0; ni < 6; ++ni)
        acc[mi][ni] = mfma16(bfv[ni], af[mi], acc[mi][ni]);
    if (kt < 11) {
      const int nxt = cur ^ 1;
      union { ivec4 v; unsigned short u[8]; } ua, ub;
      ua.v = g10; ub.v = g11;
      #pragma unroll
      for (int e = 0; e < 8; ++e) {
        const int j = jb1 + e;
        const unsigned int pk = (unsigned int)ua.u[e] | ((unsigned int)ub.u[e] << 16);
        *(unsigned int*)&Bs[nxt][j * 32 + (((kp1 >> 2) ^ ((j >> 3) & 3)) << 3) + ((kp1 & 3) << 1)] = pk;
      }
      if (two) {
        ua.v = g20; ub.v = g21;
        #pragma unroll
        for (int e = 0; e < 8; ++e) {
          const int j = jb2 + e;
          const unsigned int pk = (unsigned int)ua.u[e] | ((unsigned int)ub.u[e] << 16);
          *(unsigned int*)&Bs[nxt][j * 32 + (((kp2 >> 2) ^ ((j >> 3) & 3)) << 3) + ((kp2 & 3) << 1)] = pk;
        }
      }
    }
  }

  bf16* op = o_t + (size_t)c * PTOT;
  #pragma unroll
  for (int mi = 0; mi < 6; ++mi) {
    const int irow = i0 + wm + mi * 16 + fr;
    #pragma unroll
    for (int ni = 0; ni < 6; ++ni) {
      const int jcol = j0 + wn + ni * 16 + fq * 4;
      bf16x4 pk;
      #pragma unroll
      for (int r = 0; r < 4; ++r) pk[r] = (bf16)acc[mi][ni][r];
      *(bf16x4*)(op + (size_t)irow * N384 + jcol) = pk;
    }
  }
}

// ---------------------------------------------------------------------------
// k3 v2 (frozen): out = x + (o @ W_z + b_z). 64 positions/block.
// ---------------------------------------------------------------------------
__global__ __launch_bounds__(256) void k3_out(
    const bf16* __restrict__ o_t, const bf16* __restrict__ wtz,
    const float* __restrict__ x, const float* __restrict__ bz,
    float* __restrict__ out)
{
  __shared__ __align__(16) bf16 Ao[64 * 128];
  const int t = threadIdx.x, l = t & 63, w = t >> 6;
  const int fr = l & 15, fq = l >> 4;
  const int p0 = blockIdx.x << 6;
  const int ps = t & 7, cb = t >> 3;   // p-seg, ch-pair base

  #pragma unroll
  for (int rep = 0; rep < 2; ++rep) {
    const int cc = cb + 32 * rep;      // ch-pair index 0..63
    ivec4 d0 = *(const ivec4*)(o_t + (size_t)(2 * cc) * PTOT + p0 + ps * 8);
    ivec4 d1 = *(const ivec4*)(o_t + (size_t)(2 * cc + 1) * PTOT + p0 + ps * 8);
    union { ivec4 v; unsigned short u[8]; } ua, ub;
    ua.v = d0; ub.v = d1;
    #pragma unroll
    for (int e = 0; e < 8; ++e) {
      const int p = ps * 8 + e;
      const unsigned int pk = (unsigned int)ua.u[e] | ((unsigned int)ub.u[e] << 16);
      *(unsigned int*)&Ao[p * 128 + (((cc >> 2) ^ (p & 15)) << 3) + ((cc & 3) << 1)] = pk;
    }
  }
  __syncthreads();

  bf16x8 af[4];
  #pragma unroll
  for (int ks = 0; ks < 4; ++ks) {
    const int p = w * 16 + fr;         // p & 15 == fr
    af[ks] = *(const bf16x8*)&Ao[p * 128 + (((ks * 4 + fq) ^ fr) << 3)];
  }

  const bf16* wzf = wtz + l * 8;
  f32x4 acc[8];
  #pragma unroll
  for (int n = 0; n < 8; ++n) acc[n] = (f32x4){0.f, 0.f, 0.f, 0.f};
  #pragma unroll
  for (int n = 0; n < 8; ++n)
    #pragma unroll
    for (int ks = 0; ks < 4; ++ks) {
      const bf16x8 bfv = *(const bf16x8*)(wzf + ((n * 4 + ks) << 9));
      acc[n] = mfma16(bfv, af[ks], acc[n]);
    }

  const int pp = p0 + w * 16 + fr;
  #pragma unroll
  for (int n = 0; n < 8; ++n) {
    const int ch = n * 16 + fq * 4;
    const f32x4 b4 = *(const f32x4*)(bz + ch);
    const size_t idx = (size_t)pp * 128 + ch;
    const f32x4 x4 = *(const f32x4*)(x + idx);
    f32x4 o4;
    #pragma unroll
    for (int r = 0; r < 4; ++r) o4[r] = x4[r] + acc[n][r] + b4[r];
    *(f32x4*)(out + idx) = o4;
  }
}

// ---------------------------------------------------------------------------
extern "C" void kernel_launch(void* const* d_in, const int* in_sizes, int n_in,
                              void* d_out, int out_size, void* d_ws, size_t ws_size,
                              hipStream_t stream) {
  const float* x     = (const float*)d_in[0];
  const float* mask  = (const float*)d_in[1];
  const float* gamma = (const float*)d_in[2];
  const float* beta  = (const float*)d_in[3];
  const float* Wap   = (const float*)d_in[4];
  const float* bap   = (const float*)d_in[5];
  const float* Wag   = (const float*)d_in[6];
  const float* Wbp   = (const float*)d_in[7];
  const float* bbp   = (const float*)d_in[8];
  const float* Wbg   = (const float*)d_in[9];
  const float* Wz    = (const float*)d_in[10];
  const float* bz    = (const float*)d_in[11];

  char* ws = (char*)d_ws;
  bf16* wt  = (bf16*)ws;                         // 5*128*128 bf16 = 160KB
  bf16* a_t = (bf16*)(ws + 163840);              // [128][147456] bf16
  bf16* b_t = a_t + (size_t)128 * PTOT;
  bf16* o_t = b_t + (size_t)128 * PTOT;
  float* out = (float*)d_out;

  k_prep<<<40, 256, 0, stream>>>(Wap, Wag, Wbp, Wbg, Wz, wt);
  k1_ln_proj<<<1152, 256, 0, stream>>>(x, mask, gamma, beta, bap, bbp, wt, a_t, b_t);
  k2_tri<<<512, 256, 0, stream>>>(a_t, b_t, o_t);
  k3_out<<<2304, 256, 0, stream>>>(o_t, wt + 4 * 16384, x, bz, out);
}

// Round 17
// 118.118 us; speedup vs baseline: 1.0900x; 1.0705x over previous
//
#include <hip/hip_runtime.h>

typedef __bf16 bf16;
typedef bf16 bf16x4 __attribute__((ext_vector_type(4)));
typedef bf16 bf16x8 __attribute__((ext_vector_type(8)));
typedef float f32x4 __attribute__((ext_vector_type(4)));
typedef int ivec4 __attribute__((ext_vector_type(4)));

#define PTOT 147456   // 384*384
#define N384 384

static __device__ __forceinline__ f32x4 mfma16(bf16x8 a, bf16x8 b, f32x4 c) {
  return __builtin_amdgcn_mfma_f32_16x16x32_bf16(a, b, c, 0, 0, 0);
}

// async global->LDS, 16B per lane: LDS dest = base + lane*16 (wave-uniform base)
static __device__ __forceinline__ void gload_lds16(const bf16* g, bf16* lds) {
  __builtin_amdgcn_global_load_lds(
      (const __attribute__((address_space(1))) void*)g,
      (__attribute__((address_space(3))) void*)lds, 16, 0, 0);
}

// ---------------------------------------------------------------------------
// k_prep (40 blocks = 5 mats x 8 ch-tiles): repack weights to bf16 frag order.
// m<4: phase-interleaved for k1: wt[ ((n*16 + m*4 + ks)*64 + l)*8 + e ]
//      = W[k=ks*32+(l>>4)*8+e][ch=n*16+(l&15)]
// m==4 (W_z): wtz[ ((n*4+ks)*64 + l)*8 + e ] at wt+4*16384 (for k3).
// ---------------------------------------------------------------------------
__global__ __launch_bounds__(256) void k_prep(
    const float* __restrict__ w0, const float* __restrict__ w1,
    const float* __restrict__ w2, const float* __restrict__ w3,
    const float* __restrict__ w4, bf16* __restrict__ wt)
{
  const int m = blockIdx.x >> 3, n = blockIdx.x & 7;
  const float* src = (m == 0) ? w0 : (m == 1) ? w1 : (m == 2) ? w2 : (m == 3) ? w3 : w4;
  const int t = threadIdx.x;
  const int ks = t >> 6, l = t & 63;
  const int ch = n * 16 + (l & 15);
  const int kb = ks * 32 + (l >> 4) * 8;
  bf16 tmp[8] __attribute__((aligned(16)));
  #pragma unroll
  for (int e = 0; e < 8; ++e)
    tmp[e] = (bf16)src[(size_t)(kb + e) * 128 + ch];
  bf16* dst = (m < 4)
      ? wt + (size_t)((n * 16 + m * 4 + ks) * 64 + l) * 8
      : wt + 4 * 16384 + (size_t)((n * 4 + ks) * 64 + l) * 8;
  *(ivec4*)dst = *(const ivec4*)tmp;
}

// ---------------------------------------------------------------------------
// k1 v9 (best known, ~65us): LayerNorm + 4 projections + register gating.
// 256 threads (4 waves), 64 positions. Wave w: pair=w&1, pos-half=w>>1.
// LDS 32 KB -> 5 blocks/CU. xn (16 KB) doubles as the odd-phase weight
// buffer; immediate stores; counted vmcnt(2) + raw barrier per phase.
// NOTE (R7-R16 lessons): 64-pos/4-wave geometry + immediate stores is the
// only shape without WRITE/FETCH amplification; all store-deferral,
// barrier-free, and 128-pos variants regressed.
// ---------------------------------------------------------------------------
__global__ __launch_bounds__(256, 5) void k1_ln_proj(
    const float* __restrict__ x, const float* __restrict__ mask,
    const float* __restrict__ gamma, const float* __restrict__ beta,
    const float* __restrict__ bap, const float* __restrict__ bbp,
    const bf16* __restrict__ wt,
    bf16* __restrict__ a_t, bf16* __restrict__ b_t)
{
  __shared__ __align__(16) bf16 xnb[8192];   // 16 KB: xn, then odd-phase wbuf
  __shared__ __align__(16) bf16 wba[8192];   // 16 KB: even-phase wbuf

  const int t = threadIdx.x;
  const int l = t & 63;
  const int w = t >> 6;
  const int p0 = blockIdx.x << 6;
  const int fr = l & 15, fq = l >> 4;
  const int pair = w & 1;
  const int prow0 = (w >> 1) * 32;

  // ---- issue phase-0 weight staging (async; overlaps LN) ----
  const bf16* wsrc = wt + l * 8;
  const int c0 = w * 4;
  #pragma unroll
  for (int j = 0; j < 4; ++j)
    gload_lds16(wsrc + ((c0 + j) << 9), wba + (c0 + j) * 512);

  // ---- mask -> registers (broadcast 16B loads, L2) ----
  f32x4 m4r[2];
  m4r[0] = *(const f32x4*)(mask + p0 + prow0 + fq * 4);
  m4r[1] = *(const f32x4*)(mask + p0 + prow0 + 16 + fq * 4);

  // ---- LayerNorm: 2 rounds x 32 rows; thread -> row (t>>3), 16 channels ----
  const int csub = (t & 7) << 4;
  f32x4 g4[4], bt4[4];
  #pragma unroll
  for (int i = 0; i < 4; ++i) {
    g4[i]  = *(const f32x4*)(gamma + csub + i * 4);
    bt4[i] = *(const f32x4*)(beta  + csub + i * 4);
  }
  #pragma unroll
  for (int it = 0; it < 2; ++it) {
    const int row = (t >> 3) + it * 32;
    f32x4 v[4];
    const float* xb = x + (size_t)(p0 + row) * 128 + csub;
    #pragma unroll
    for (int i = 0; i < 4; ++i) v[i] = *(const f32x4*)(xb + i * 4);

    float s = 0.f, s2 = 0.f;
    #pragma unroll
    for (int i = 0; i < 4; ++i)
      #pragma unroll
      for (int j = 0; j < 4; ++j) { const float f = v[i][j]; s += f; s2 += f * f; }
    #pragma unroll
    for (int m = 1; m < 8; m <<= 1) {
      s  += __shfl_xor(s, m, 64);
      s2 += __shfl_xor(s2, m, 64);
    }
    const float mu = s * (1.f / 128.f);
    const float rs = rsqrtf(s2 * (1.f / 128.f) - mu * mu + 1e-5f);

    bf16x8 xv0, xv1;
    #pragma unroll
    for (int i = 0; i < 4; ++i)
      #pragma unroll
      for (int j = 0; j < 4; ++j) {
        const float f = (v[i][j] - mu) * rs * g4[i][j] + bt4[i][j];
        const int e = i * 4 + j;
        if (e < 8) xv0[e] = (bf16)f; else xv1[e - 8] = (bf16)f;
      }
    const int sw = (row & 7) << 3;
    *(bf16x8*)&xnb[row * 128 + (csub ^ sw)]       = xv0;
    *(bf16x8*)&xnb[row * 128 + ((csub + 8) ^ sw)] = xv1;
  }
  __syncthreads();   // xn visible + phase-0 weights landed (full drain)

  // ---- A fragments (held in registers for the whole kernel) ----
  bf16x8 af[2][4];
  #pragma unroll
  for (int mi = 0; mi < 2; ++mi)
    #pragma unroll
    for (int ks = 0; ks < 4; ++ks) {
      const int row = prow0 + mi * 16 + fr;
      af[mi][ks] = *(const bf16x8*)&xnb[row * 128 + ((ks * 32 + fq * 8) ^ ((fr & 7) << 3))];
    }
  __syncthreads();   // all waves read xn; safe to overwrite as weight buffer

  const float* bp = pair ? bbp : bap;
  bf16* dst = pair ? b_t : a_t;
  float biasv[8];
  #pragma unroll
  for (int p = 0; p < 8; ++p) biasv[p] = bp[p * 16 + fr];

  #pragma unroll
  for (int p = 0; p < 8; ++p) {
    if (p < 7) {   // stage phase p+1 into the idle buffer (odd -> xnb)
      bf16* nb = ((p + 1) & 1) ? xnb : wba;
      #pragma unroll
      for (int j = 0; j < 4; ++j)
        gload_lds16(wsrc + (((p + 1) * 16 + c0 + j) << 9), nb + (c0 + j) * 512);
      __builtin_amdgcn_sched_barrier(0);   // pin gload issue at phase top
    }
    const bf16* buf = ((p & 1) ? xnb : wba) + l * 8;
    const bf16* wpl = buf + (pair * 2) * 2048;       // proj chunks (4 ks)
    const bf16* wgl = buf + (pair * 2 + 1) * 2048;   // gate chunks

    f32x4 aG0 = (f32x4){0.f, 0.f, 0.f, 0.f};
    f32x4 aG1 = (f32x4){0.f, 0.f, 0.f, 0.f};
    #pragma unroll
    for (int ks = 0; ks < 4; ++ks) {
      const bf16x8 bv = *(const bf16x8*)(wgl + ks * 512);
      aG0 = mfma16(af[0][ks], bv, aG0);
      aG1 = mfma16(af[1][ks], bv, aG1);
    }
    f32x4 aP0 = (f32x4){0.f, 0.f, 0.f, 0.f};
    f32x4 aP1 = (f32x4){0.f, 0.f, 0.f, 0.f};
    #pragma unroll
    for (int ks = 0; ks < 4; ++ks) {
      const bf16x8 bv = *(const bf16x8*)(wpl + ks * 512);
      aP0 = mfma16(af[0][ks], bv, aP0);
      aP1 = mfma16(af[1][ks], bv, aP1);
    }
    const int ch = p * 16 + fr;
    const float bias = biasv[p];
    #pragma unroll
    for (int mi = 0; mi < 2; ++mi) {
      const f32x4 aG = mi ? aG1 : aG0;
      const f32x4 aP = mi ? aP1 : aP0;
      const int pb = prow0 + mi * 16 + fq * 4;
      const f32x4 m4 = m4r[mi];
      bf16x4 pk;
      #pragma unroll
      for (int r = 0; r < 4; ++r) {
        const float sg = 1.f / (1.f + __expf(-aG[r]));
        pk[r] = (bf16)((aP[r] + bias) * sg * m4[r]);
      }
      *(bf16x4*)(dst + (size_t)ch * PTOT + p0 + pb) = pk;
    }
    if (p < 7) {
      asm volatile("s_waitcnt vmcnt(2)" ::: "memory");
      __builtin_amdgcn_sched_barrier(0);
      __builtin_amdgcn_s_barrier();
    }
  }
}

// ---------------------------------------------------------------------------
// k2 v4 (frozen): per-channel GEMM O_c = A_c * B_c (384x384), 192x192 tile,
// BK=32, double-buffered, ONE barrier per kt. 36 MFMA/wave/kt.
// Grid 512 = 8 XCD x 16 ch x 4 tiles -> exactly 2 blocks/CU.
// ---------------------------------------------------------------------------
__global__ __launch_bounds__(256, 2) void k2_tri(
    const bf16* __restrict__ a_t, const bf16* __restrict__ b_t, bf16* __restrict__ o_t)
{
  __shared__ __align__(16) bf16 As[2][6144];   // [row 192][k 32] swizzled
  __shared__ __align__(16) bf16 Bs[2][6144];   // [j 192][k 32] swizzled
  const int t = threadIdx.x, l = t & 63, w = t >> 6;
  const int fr = l & 15, fq = l >> 4;
  const int bid = blockIdx.x;
  const int xcd = bid & 7, idx = bid >> 3;
  const int c  = xcd * 16 + (idx >> 2);        // channel
  const int ti = idx & 3;                      // tile 0..3
  const int i0 = (ti >> 1) * 192, j0 = (ti & 1) * 192;
  const bf16* ap = a_t + (size_t)c * PTOT;
  const bf16* bp = b_t + (size_t)c * PTOT;
  const int wm = (w >> 1) * 96, wn = (w & 1) * 96;
  const int arA = w * 48 + (l >> 2);
  const int kp1 = t >> 4, jb1 = (t & 15) * 8;          // all threads
  const int kp2 = t >> 3, jb2 = 128 + (t & 7) * 8;     // t < 128 only
  const bool two = t < 128;

  f32x4 acc[6][6];
  #pragma unroll
  for (int mi = 0; mi < 6; ++mi)
    #pragma unroll
    for (int ni = 0; ni < 6; ++ni) acc[mi][ni] = (f32x4){0.f, 0.f, 0.f, 0.f};

  ivec4 g10, g11, g20, g21;
  #pragma unroll
  for (int jcall = 0; jcall < 3; ++jcall) {
    const int row = arA + jcall * 16;
    const int scol = ((l & 3) ^ ((row >> 3) & 3)) << 3;
    gload_lds16(ap + (size_t)(i0 + row) * N384 + scol, &As[0][w * 1536 + jcall * 512]);
  }
  g10 = *(const ivec4*)(bp + (size_t)(2 * kp1) * N384 + j0 + jb1);
  g11 = *(const ivec4*)(bp + (size_t)(2 * kp1 + 1) * N384 + j0 + jb1);
  if (two) {
    g20 = *(const ivec4*)(bp + (size_t)(2 * kp2) * N384 + j0 + jb2);
    g21 = *(const ivec4*)(bp + (size_t)(2 * kp2 + 1) * N384 + j0 + jb2);
  }
  {
    union { ivec4 v; unsigned short u[8]; } ua, ub;
    ua.v = g10; ub.v = g11;
    #pragma unroll
    for (int e = 0; e < 8; ++e) {
      const int j = jb1 + e;
      const unsigned int pk = (unsigned int)ua.u[e] | ((unsigned int)ub.u[e] << 16);
      *(unsigned int*)&Bs[0][j * 32 + (((kp1 >> 2) ^ ((j >> 3) & 3)) << 3) + ((kp1 & 3) << 1)] = pk;
    }
    if (two) {
      ua.v = g20; ub.v = g21;
      #pragma unroll
      for (int e = 0; e < 8; ++e) {
        const int j = jb2 + e;
        const unsigned int pk = (unsigned int)ua.u[e] | ((unsigned int)ub.u[e] << 16);
        *(unsigned int*)&Bs[0][j * 32 + (((kp2 >> 2) ^ ((j >> 3) & 3)) << 3) + ((kp2 & 3) << 1)] = pk;
      }
    }
  }

  for (int kt = 0; kt < 12; ++kt) {
    __syncthreads();
    const int cur = kt & 1;
    bf16x8 af[6], bfv[6];
    #pragma unroll
    for (int mi = 0; mi < 6; ++mi) {
      const int row = wm + mi * 16 + fr;
      af[mi] = *(const bf16x8*)&As[cur][row * 32 + ((fq ^ ((row >> 3) & 3)) << 3)];
    }
    #pragma unroll
    for (int ni = 0; ni < 6; ++ni) {
      const int j = wn + ni * 16 + fr;
      bfv[ni] = *(const bf16x8*)&Bs[cur][j * 32 + ((fq ^ ((j >> 3) & 3)) << 3)];
    }
    if (kt < 11) {
      const int k0 = (kt + 1) * 32;
      const int nxt = cur ^ 1;
      #pragma unroll
      for (int jcall = 0; jcall < 3; ++jcall) {
        const int row = arA + jcall * 16;
        const int scol = ((l & 3) ^ ((row >> 3) & 3)) << 3;
        gload_lds16(ap + (size_t)(i0 + row) * N384 + k0 + scol,
                    &As[nxt][w * 1536 + jcall * 512]);
      }
      g10 = *(const ivec4*)(bp + (size_t)(k0 + 2 * kp1) * N384 + j0 + jb1);
      g11 = *(const ivec4*)(bp + (size_t)(k0 + 2 * kp1 + 1) * N384 + j0 + jb1);
      if (two) {
        g20 = *(const ivec4*)(bp + (size_t)(k0 + 2 * kp2) * N384 + j0 + jb2);
        g21 = *(const ivec4*)(bp + (size_t)(k0 + 2 * kp2 + 1) * N384 + j0 + jb2);
      }
    }
    #pragma unroll
    for (int mi = 0; mi < 6; ++mi)
      #pragma unroll
      for (int ni = 0; ni < 6; ++ni)
        acc[mi][ni] = mfma16(bfv[ni], af[mi], acc[mi][ni]);
    if (kt < 11) {
      const int nxt = cur ^ 1;
      union { ivec4 v; unsigned short u[8]; } ua, ub;
      ua.v = g10; ub.v = g11;
      #pragma unroll
      for (int e = 0; e < 8; ++e) {
        const int j = jb1 + e;
        const unsigned int pk = (unsigned int)ua.u[e] | ((unsigned int)ub.u[e] << 16);
        *(unsigned int*)&Bs[nxt][j * 32 + (((kp1 >> 2) ^ ((j >> 3) & 3)) << 3) + ((kp1 & 3) << 1)] = pk;
      }
      if (two) {
        ua.v = g20; ub.v = g21;
        #pragma unroll
        for (int e = 0; e < 8; ++e) {
          const int j = jb2 + e;
          const unsigned int pk = (unsigned int)ua.u[e] | ((unsigned int)ub.u[e] << 16);
          *(unsigned int*)&Bs[nxt][j * 32 + (((kp2 >> 2) ^ ((j >> 3) & 3)) << 3) + ((kp2 & 3) << 1)] = pk;
        }
      }
    }
  }

  bf16* op = o_t + (size_t)c * PTOT;
  #pragma unroll
  for (int mi = 0; mi < 6; ++mi) {
    const int irow = i0 + wm + mi * 16 + fr;
    #pragma unroll
    for (int ni = 0; ni < 6; ++ni) {
      const int jcol = j0 + wn + ni * 16 + fq * 4;
      bf16x4 pk;
      #pragma unroll
      for (int r = 0; r < 4; ++r) pk[r] = (bf16)acc[mi][ni][r];
      *(bf16x4*)(op + (size_t)irow * N384 + jcol) = pk;
    }
  }
}

// ---------------------------------------------------------------------------
// k3 v2 (frozen, BW-floor): out = x + (o @ W_z + b_z). 64 positions/block.
// ---------------------------------------------------------------------------
__global__ __launch_bounds__(256) void k3_out(
    const bf16* __restrict__ o_t, const bf16* __restrict__ wtz,
    const float* __restrict__ x, const float* __restrict__ bz,
    float* __restrict__ out)
{
  __shared__ __align__(16) bf16 Ao[64 * 128];
  const int t = threadIdx.x, l = t & 63, w = t >> 6;
  const int fr = l & 15, fq = l >> 4;
  const int p0 = blockIdx.x << 6;
  const int ps = t & 7, cb = t >> 3;   // p-seg, ch-pair base

  #pragma unroll
  for (int rep = 0; rep < 2; ++rep) {
    const int cc = cb + 32 * rep;      // ch-pair index 0..63
    ivec4 d0 = *(const ivec4*)(o_t + (size_t)(2 * cc) * PTOT + p0 + ps * 8);
    ivec4 d1 = *(const ivec4*)(o_t + (size_t)(2 * cc + 1) * PTOT + p0 + ps * 8);
    union { ivec4 v; unsigned short u[8]; } ua, ub;
    ua.v = d0; ub.v = d1;
    #pragma unroll
    for (int e = 0; e < 8; ++e) {
      const int p = ps * 8 + e;
      const unsigned int pk = (unsigned int)ua.u[e] | ((unsigned int)ub.u[e] << 16);
      *(unsigned int*)&Ao[p * 128 + (((cc >> 2) ^ (p & 15)) << 3) + ((cc & 3) << 1)] = pk;
    }
  }
  __syncthreads();

  bf16x8 af[4];
  #pragma unroll
  for (int ks = 0; ks < 4; ++ks) {
    const int p = w * 16 + fr;         // p & 15 == fr
    af[ks] = *(const bf16x8*)&Ao[p * 128 + (((ks * 4 + fq) ^ fr) << 3)];
  }

  const bf16* wzf = wtz + l * 8;
  f32x4 acc[8];
  #pragma unroll
  for (int n = 0; n < 8; ++n) acc[n] = (f32x4){0.f, 0.f, 0.f, 0.f};
  #pragma unroll
  for (int n = 0; n < 8; ++n)
    #pragma unroll
    for (int ks = 0; ks < 4; ++ks) {
      const bf16x8 bfv = *(const bf16x8*)(wzf + ((n * 4 + ks) << 9));
      acc[n] = mfma16(bfv, af[ks], acc[n]);
    }

  const int pp = p0 + w * 16 + fr;
  #pragma unroll
  for (int n = 0; n < 8; ++n) {
    const int ch = n * 16 + fq * 4;
    const f32x4 b4 = *(const f32x4*)(bz + ch);
    const size_t idx = (size_t)pp * 128 + ch;
    const f32x4 x4 = *(const f32x4*)(x + idx);
    f32x4 o4;
    #pragma unroll
    for (int r = 0; r < 4; ++r) o4[r] = x4[r] + acc[n][r] + b4[r];
    *(f32x4*)(out + idx) = o4;
  }
}

// ---------------------------------------------------------------------------
extern "C" void kernel_launch(void* const* d_in, const int* in_sizes, int n_in,
                              void* d_out, int out_size, void* d_ws, size_t ws_size,
                              hipStream_t stream) {
  const float* x     = (const float*)d_in[0];
  const float* mask  = (const float*)d_in[1];
  const float* gamma = (const float*)d_in[2];
  const float* beta  = (const float*)d_in[3];
  const float* Wap   = (const float*)d_in[4];
  const float* bap   = (const float*)d_in[5];
  const float* Wag   = (const float*)d_in[6];
  const float* Wbp   = (const float*)d_in[7];
  const float* bbp   = (const float*)d_in[8];
  const float* Wbg   = (const float*)d_in[9];
  const float* Wz    = (const float*)d_in[10];
  const float* bz    = (const float*)d_in[11];

  char* ws = (char*)d_ws;
  bf16* wt  = (bf16*)ws;                         // 5*128*128 bf16 = 160KB
  bf16* a_t = (bf16*)(ws + 163840);              // [128][147456] bf16
  bf16* b_t = a_t + (size_t)128 * PTOT;
  bf16* o_t = b_t + (size_t)128 * PTOT;
  float* out = (float*)d_out;

  k_prep<<<40, 256, 0, stream>>>(Wap, Wag, Wbp, Wbg, Wz, wt);
  k1_ln_proj<<<2304, 256, 0, stream>>>(x, mask, gamma, beta, bap, bbp, wt, a_t, b_t);
  k2_tri<<<512, 256, 0, stream>>>(a_t, b_t, o_t);
  k3_out<<<2304, 256, 0, stream>>>(o_t, wt + 4 * 16384, x, bz, out);
}